// Round 12
// baseline (953.272 us; speedup 1.0000x reference)
//
#include <hip/hip_runtime.h>
#include <hip/hip_bf16.h>
#include <cstdint>

#define M_TOT 16384
#define K_TOT 4096
#define N_TOT 4096
#define RNK   16
#define BM 256
#define BN 128
#define BK 32
#define NTK (K_TOT / BK)   // 128 K-tiles

using bf16x8 = __attribute__((ext_vector_type(8))) __bf16;
using f32x16 = __attribute__((ext_vector_type(16))) float;

__device__ __forceinline__ unsigned short f2bf(float f) {
  union { float f; unsigned u; } v; v.f = f;
  unsigned u = v.u;
  unsigned r = (u + 0x7fffu + ((u >> 16) & 1u)) >> 16;
  return (unsigned short)r;
}

// ---------------- f32 -> bf16 conversion (W) --------------------------------
__global__ void cvt_f32_bf16(const float* __restrict__ in,
                             unsigned short* __restrict__ out, int n4) {
  int i = blockIdx.x * blockDim.x + threadIdx.x;
  int stride = gridDim.x * blockDim.x;
  for (; i < n4; i += stride) {
    float4 v = reinterpret_cast<const float4*>(in)[i];
    ushort4 o;
    o.x = f2bf(v.x); o.y = f2bf(v.y); o.z = f2bf(v.z); o.w = f2bf(v.w);
    reinterpret_cast<ushort4*>(out)[i] = o;
  }
}

// ------ fused: xb = bf16(x) (all lanes, vectorized) THEN inter from xb ------
__global__ __launch_bounds__(256) void xcvt_inter_kernel(
    const float* __restrict__ x, const int* __restrict__ eid,
    const float* __restrict__ la, unsigned short* __restrict__ xb,
    float* __restrict__ inter) {
  const int row0 = blockIdx.x * 8;
  const int t = threadIdx.x;

  const float4* xs = reinterpret_cast<const float4*>(x + (size_t)row0 * K_TOT);
  ushort4* xd = reinterpret_cast<ushort4*>(xb + (size_t)row0 * K_TOT);
#pragma unroll
  for (int i = 0; i < 32; ++i) {
    float4 v = xs[t + 256 * i];
    ushort4 o;
    o.x = f2bf(v.x); o.y = f2bf(v.y); o.z = f2bf(v.z); o.w = f2bf(v.w);
    xd[t + 256 * i] = o;
  }
  __syncthreads();   // compiler drains vmcnt(0) before the barrier

  const int e = eid[row0 >> 11];
  const int r = t >> 4;
  const int j = t & 15;
  const float* lar = la + ((size_t)e * RNK + r) * K_TOT;
  const unsigned short* xr = xb + (size_t)row0 * K_TOT;
  float acc[8] = {0.f,0.f,0.f,0.f,0.f,0.f,0.f,0.f};
  union bu { unsigned u; float f; };
  for (int c = 0; c < K_TOT / 128; ++c) {
    int k = c * 128 + j * 8;
    float4 la0 = *reinterpret_cast<const float4*>(lar + k);
    float4 la1 = *reinterpret_cast<const float4*>(lar + k + 4);
#pragma unroll
    for (int q = 0; q < 8; ++q) {
      uint4 u = *reinterpret_cast<const uint4*>(xr + (size_t)q * K_TOT + k);
      bu a, b;
      float s;
      a.u = u.x << 16; b.u = u.x & 0xffff0000u;
      s  = a.f * la0.x + b.f * la0.y;
      a.u = u.y << 16; b.u = u.y & 0xffff0000u;
      s += a.f * la0.z + b.f * la0.w;
      a.u = u.z << 16; b.u = u.z & 0xffff0000u;
      s += a.f * la1.x + b.f * la1.y;
      a.u = u.w << 16; b.u = u.w & 0xffff0000u;
      s += a.f * la1.z + b.f * la1.w;
      acc[q] += s;
    }
  }
#pragma unroll
  for (int q = 0; q < 8; ++q) {
    float a = acc[q];
    a += __shfl_xor(a, 1);
    a += __shfl_xor(a, 2);
    a += __shfl_xor(a, 4);
    a += __shfl_xor(a, 8);
    acc[q] = a;
  }
  if (j == 0) {
#pragma unroll
    for (int q = 0; q < 8; ++q)
      inter[(size_t)(row0 + q) * RNK + r] = acc[q];
  }
}

// ---- 256x128 dbuf GEMM, 32x32x16 MFMA, 2 blocks/CU + fused LoRA epilogue ---
#define GLD16(gsrc, ldst)                                                      \
  __builtin_amdgcn_global_load_lds(                                            \
      (__attribute__((address_space(1))) const void*)(gsrc),                   \
      (__attribute__((address_space(3))) void*)(ldst), 16, 0, 0)

#define FENCE() asm volatile("" ::: "memory")
#define BARRIER() do { FENCE(); __builtin_amdgcn_s_barrier(); FENCE(); } while (0)

// stage K-tile T: A 256x32 (16KB, 2 calls) + B 128x32 (8KB, 1 call) -> buf[T&1]
#define STAGE(T) do {                                                          \
  const int _b = ((T) & 1) ? 24576 : 0;                                        \
  const size_t _go = (size_t)(T) * BK;                                         \
  GLD16(gA + _go,                       smem + _b + ldsw);                     \
  GLD16(gA + (size_t)128 * K_TOT + _go, smem + _b + 8192 + ldsw);              \
  GLD16(gB + _go,                       smem + _b + 16384 + ldsw);             \
} while (0)

__global__ __launch_bounds__(512, 4) void gemm_kernel(
    const unsigned short* __restrict__ xb, const unsigned short* __restrict__ wb,
    const float* __restrict__ bias, const float* __restrict__ inter,
    const float* __restrict__ lb, const int* __restrict__ eid,
    float* __restrict__ out) {
  __shared__ unsigned char smem[49152];   // dbuf x (A 16KB + B 8KB)

  const int bid = blockIdx.x;
  const int swz = (bid & 7) * 256 + (bid >> 3);   // 2048 wgs, bijective
  const int bm = swz >> 5, bn = swz & 31;         // 64 bm x 32 bn, bm-major
  const int brow = bm * BM, bcol = bn * BN;
  const int t = threadIdx.x;
  const int w = t >> 6, l = t & 63;
  const int wr = w >> 1, wc = w & 1;              // 4x2 wave grid, wave = 64x64 out
  const int l31 = l & 31;
  const int l32 = l >> 5;
  const int lsw = (l >> 1) & 3;                   // f(row) = (row>>1)&3, row bits 1-2 = l bits 1-2

  // staging source (pre-swizzled; inverse of the ds_read swizzle, rule 21).
  // GLD row = t>>2 (+128 for A call 2: bits 1-2 unchanged) -> f = (t>>3)&3.
  const int srow = t >> 2;
  const int scol = ((t & 3) ^ ((t >> 3) & 3)) << 3;
  const unsigned short* gA = xb + (size_t)(brow + srow) * K_TOT + scol;
  const unsigned short* gB = wb + (size_t)(bcol + srow) * K_TOT + scol;
  const int ldsw = w << 10;                       // 8 waves x 1KB per 8KB call

  f32x16 acc[2][2];
#pragma unroll
  for (int i = 0; i < 2; ++i)
#pragma unroll
    for (int n = 0; n < 2; ++n)
#pragma unroll
      for (int r = 0; r < 16; ++r)
        acc[i][n][r] = 0.f;
  bf16x8 aF[2][2], bF[2][2];

  // prologue: stage tile 0; counted vmcnt keeps next tile's loads in flight.
  STAGE(0);

  for (int T = 0; T < NTK; ++T) {
    const int bo = (T & 1) ? 24576 : 0;
    if (T + 1 < NTK) {
      STAGE(T + 1);                                   // -> other buffer
      asm volatile("s_waitcnt vmcnt(3)" ::: "memory");  // retire tile T's 3
    } else {
      asm volatile("s_waitcnt vmcnt(0)" ::: "memory");
    }
    BARRIER();
    // fragment reads: row-major 64B rows, swizzled 16B slot
#pragma unroll
    for (int ar = 0; ar < 2; ++ar)
#pragma unroll
      for (int ks = 0; ks < 2; ++ks)
        aF[ar][ks] = *reinterpret_cast<const bf16x8*>(
            smem + bo + (wr * 64 + ar * 32 + l31) * 64 +
            ((((ks << 1) + l32) ^ lsw) << 4));
#pragma unroll
    for (int n = 0; n < 2; ++n)
#pragma unroll
      for (int ks = 0; ks < 2; ++ks)
        bF[n][ks] = *reinterpret_cast<const bf16x8*>(
            smem + bo + 16384 + (wc * 64 + n * 32 + l31) * 64 +
            ((((ks << 1) + l32) ^ lsw) << 4));
    __builtin_amdgcn_s_setprio(1);
#pragma unroll
    for (int ar = 0; ar < 2; ++ar)
#pragma unroll
      for (int n = 0; n < 2; ++n) {
        acc[ar][n] = __builtin_amdgcn_mfma_f32_32x32x16_bf16(
            aF[ar][0], bF[n][0], acc[ar][n], 0, 0, 0);
        acc[ar][n] = __builtin_amdgcn_mfma_f32_32x32x16_bf16(
            aF[ar][1], bF[n][1], acc[ar][n], 0, 0, 0);
      }
    __builtin_amdgcn_s_setprio(0);
    BARRIER();   // all reads of buf done before next iteration's STAGE
  }

  // ---------------- epilogue: bias + 2.0 * inter @ lb^T ----------------
  float* interS = reinterpret_cast<float*>(smem);           // 256 x 16 f32 (broadcast)
  float* lbS    = reinterpret_cast<float*>(smem + 16384);   // 128 x 17 f32 (padded)
  const int e = eid[brow >> 11];
  const float* interG = inter + (size_t)brow * RNK;
  const float* lbG    = lb + ((size_t)e * N_TOT + bcol) * RNK;
#pragma unroll
  for (int q = 0; q < 8; ++q) {
    const int idx = t + 512 * q;
    interS[idx] = interG[idx];
  }
#pragma unroll
  for (int q = 0; q < 4; ++q) {
    const int idx = t + 512 * q;
    lbS[(idx >> 4) * 17 + (idx & 15)] = lbG[idx];
  }
  __syncthreads();

  // C/D layout (32x32): col = lane&31, row = (r&3) + 8*(r>>2) + 4*(lane>>5)
  const int ccol = wc * 64 + l31;
  float bv[2];
#pragma unroll
  for (int n = 0; n < 2; ++n)
    bv[n] = bias[bcol + ccol + n * 32];

#pragma unroll
  for (int ar = 0; ar < 2; ++ar) {
#pragma unroll
    for (int r = 0; r < 16; ++r) {
      const int ml = wr * 64 + ar * 32 + (r & 3) + 8 * (r >> 2) + 4 * l32;
      const float* iv = interS + ml * RNK;
      const size_t orow = (size_t)(brow + ml) * N_TOT + bcol;
#pragma unroll
      for (int n = 0; n < 2; ++n) {
        const int ol = ccol + n * 32;
        const float* lv = lbS + ol * 17;
        float d = 0.f;
#pragma unroll
        for (int rr = 0; rr < RNK; ++rr) d += iv[rr] * lv[rr];
        out[orow + ol] = acc[ar][n][r] + bv[n] + 2.0f * d;
      }
    }
  }
}

extern "C" void kernel_launch(void* const* d_in, const int* in_sizes, int n_in,
                              void* d_out, int out_size, void* d_ws, size_t ws_size,
                              hipStream_t stream) {
  const float* x    = (const float*)d_in[0];
  const int*   eid  = (const int*)d_in[1];
  const float* W    = (const float*)d_in[2];
  const float* bias = (const float*)d_in[3];
  const float* la   = (const float*)d_in[4];
  const float* lb   = (const float*)d_in[5];
  float* out = (float*)d_out;

  // workspace layout: xb (134MB) | wb (33.5MB) | inter (1MB)
  unsigned short* xb = (unsigned short*)d_ws;
  unsigned short* wb = xb + (size_t)M_TOT * K_TOT;
  float* inter = (float*)(wb + (size_t)N_TOT * K_TOT);

  cvt_f32_bf16<<<2048, 256, 0, stream>>>(W, wb, (N_TOT * K_TOT) / 4);
  xcvt_inter_kernel<<<M_TOT / 8, 256, 0, stream>>>(x, eid, la, xb, inter);

  gemm_kernel<<<(M_TOT / BM) * (N_TOT / BN), 512, 0, stream>>>(
      xb, wb, bias, inter, lb, eid, out);
}

// Round 13
// 818.427 us; speedup vs baseline: 1.1648x; 1.1648x over previous
//
#include <hip/hip_runtime.h>
#include <hip/hip_bf16.h>
#include <cstdint>

#define M_TOT 16384
#define K_TOT 4096
#define N_TOT 4096
#define RNK   16
#define BM 256
#define BN 256
#define BK 32
#define NTK (K_TOT / BK)   // 128 K-tiles

using bf16x8 = __attribute__((ext_vector_type(8))) __bf16;
using f32x16 = __attribute__((ext_vector_type(16))) float;

__device__ __forceinline__ unsigned short f2bf(float f) {
  union { float f; unsigned u; } v; v.f = f;
  unsigned u = v.u;
  unsigned r = (u + 0x7fffu + ((u >> 16) & 1u)) >> 16;
  return (unsigned short)r;
}

// ---------------- f32 -> bf16 conversion (W) --------------------------------
__global__ void cvt_f32_bf16(const float* __restrict__ in,
                             unsigned short* __restrict__ out, int n4) {
  int i = blockIdx.x * blockDim.x + threadIdx.x;
  int stride = gridDim.x * blockDim.x;
  for (; i < n4; i += stride) {
    float4 v = reinterpret_cast<const float4*>(in)[i];
    ushort4 o;
    o.x = f2bf(v.x); o.y = f2bf(v.y); o.z = f2bf(v.z); o.w = f2bf(v.w);
    reinterpret_cast<ushort4*>(out)[i] = o;
  }
}

// ------ fused: xb = bf16(x) (all lanes, vectorized) THEN inter from xb ------
__global__ __launch_bounds__(256) void xcvt_inter_kernel(
    const float* __restrict__ x, const int* __restrict__ eid,
    const float* __restrict__ la, unsigned short* __restrict__ xb,
    float* __restrict__ inter) {
  const int row0 = blockIdx.x * 8;
  const int t = threadIdx.x;

  const float4* xs = reinterpret_cast<const float4*>(x + (size_t)row0 * K_TOT);
  ushort4* xd = reinterpret_cast<ushort4*>(xb + (size_t)row0 * K_TOT);
#pragma unroll
  for (int i = 0; i < 32; ++i) {
    float4 v = xs[t + 256 * i];
    ushort4 o;
    o.x = f2bf(v.x); o.y = f2bf(v.y); o.z = f2bf(v.z); o.w = f2bf(v.w);
    xd[t + 256 * i] = o;
  }
  __syncthreads();   // compiler drains vmcnt(0) before the barrier

  const int e = eid[row0 >> 11];
  const int r = t >> 4;
  const int j = t & 15;
  const float* lar = la + ((size_t)e * RNK + r) * K_TOT;
  const unsigned short* xr = xb + (size_t)row0 * K_TOT;
  float acc[8] = {0.f,0.f,0.f,0.f,0.f,0.f,0.f,0.f};
  union bu { unsigned u; float f; };
  for (int c = 0; c < K_TOT / 128; ++c) {
    int k = c * 128 + j * 8;
    float4 la0 = *reinterpret_cast<const float4*>(lar + k);
    float4 la1 = *reinterpret_cast<const float4*>(lar + k + 4);
#pragma unroll
    for (int q = 0; q < 8; ++q) {
      uint4 u = *reinterpret_cast<const uint4*>(xr + (size_t)q * K_TOT + k);
      bu a, b;
      float s;
      a.u = u.x << 16; b.u = u.x & 0xffff0000u;
      s  = a.f * la0.x + b.f * la0.y;
      a.u = u.y << 16; b.u = u.y & 0xffff0000u;
      s += a.f * la0.z + b.f * la0.w;
      a.u = u.z << 16; b.u = u.z & 0xffff0000u;
      s += a.f * la1.x + b.f * la1.y;
      a.u = u.w << 16; b.u = u.w & 0xffff0000u;
      s += a.f * la1.z + b.f * la1.w;
      acc[q] += s;
    }
  }
#pragma unroll
  for (int q = 0; q < 8; ++q) {
    float a = acc[q];
    a += __shfl_xor(a, 1);
    a += __shfl_xor(a, 2);
    a += __shfl_xor(a, 4);
    a += __shfl_xor(a, 8);
    acc[q] = a;
  }
  if (j == 0) {
#pragma unroll
    for (int q = 0; q < 8; ++q)
      inter[(size_t)(row0 + q) * RNK + r] = acc[q];
  }
}

// -- 256x256 GEMM, BK=32, 4-deep LDS pipeline, 32x32x16 MFMA + LoRA epilogue -
#define GLD16(gsrc, ldst)                                                      \
  __builtin_amdgcn_global_load_lds(                                            \
      (__attribute__((address_space(1))) const void*)(gsrc),                   \
      (__attribute__((address_space(3))) void*)(ldst), 16, 0, 0)

#define FENCE() asm volatile("" ::: "memory")
#define BARRIER() do { FENCE(); __builtin_amdgcn_s_barrier(); FENCE(); } while (0)

// stage K-tile T (A 256x32 = 16KB + B 256x32 = 16KB) -> buf[T&3]; 4 GLD16.
#define STAGE(T) do {                                                          \
  const int _b = ((T) & 3) << 15;                                              \
  const size_t _go = (size_t)(T) * BK;                                         \
  GLD16(gA + _go,                       smem + _b + ldsw);                     \
  GLD16(gA + (size_t)128 * K_TOT + _go, smem + _b + 8192 + ldsw);              \
  GLD16(gB + _go,                       smem + _b + 16384 + ldsw);             \
  GLD16(gB + (size_t)128 * K_TOT + _go, smem + _b + 24576 + ldsw);             \
} while (0)

__global__ __launch_bounds__(512, 2) void gemm_kernel(
    const unsigned short* __restrict__ xb, const unsigned short* __restrict__ wb,
    const float* __restrict__ bias, const float* __restrict__ inter,
    const float* __restrict__ lb, const int* __restrict__ eid,
    float* __restrict__ out) {
  __shared__ unsigned char smem[131072];   // 4 bufs x (A 16KB + B 16KB)

  const int bid = blockIdx.x;
  const int swz = (bid & 7) * 128 + (bid >> 3);   // 1024 wgs, bijective
  const int bm = swz >> 4, bn = swz & 15;         // bm-major (best FETCH map)
  const int brow = bm * BM, bcol = bn * BN;
  const int t = threadIdx.x;
  const int w = t >> 6, l = t & 63;
  const int wr = w >> 2, wc = w & 3;              // 2 x 4 wave grid, wave = 128x64 out
  const int l31 = l & 31;
  const int l32 = l >> 5;
  const int lsw = (l >> 1) & 3;                   // f(row) = (row>>1)&3

  // staging source (pre-swizzled inverse of ds_read swizzle; rule 21).
  // GLD row = t>>2 (+128 for 2nd call: bits 1-2 unchanged) -> f = (t>>3)&3.
  const int srow = t >> 2;
  const int scol = ((t & 3) ^ ((t >> 3) & 3)) << 3;
  const unsigned short* gA = xb + (size_t)(brow + srow) * K_TOT + scol;
  const unsigned short* gB = wb + (size_t)(bcol + srow) * K_TOT + scol;
  const int ldsw = w << 10;                       // 8 waves x 1KB per 8KB call

  f32x16 acc[4][2];
#pragma unroll
  for (int i = 0; i < 4; ++i)
#pragma unroll
    for (int n = 0; n < 2; ++n)
#pragma unroll
      for (int r = 0; r < 16; ++r)
        acc[i][n][r] = 0.f;
  bf16x8 aF[4][2], bF[2][2];

  // prologue: stage 3 tiles; retire tile 0 (vmcnt(8) = 12 outstanding - 4).
  STAGE(0); STAGE(1); STAGE(2);
  asm volatile("s_waitcnt vmcnt(8)" ::: "memory");
  BARRIER();

  for (int T = 0; T < NTK; ++T) {
    const int bo = (T & 3) << 15;
    // steady state: issue T+3, wait retires T+1's loads -- issued 3 tiles
    // (~9K cyc) ago, so the wait is a no-op; buf[T] was retired last tile.
    if (T + 3 < NTK) {
      STAGE(T + 3);
      asm volatile("s_waitcnt vmcnt(8)" ::: "memory");
    } else if (T + 2 < NTK) {
      asm volatile("s_waitcnt vmcnt(8)" ::: "memory");
    } else if (T + 1 < NTK) {
      asm volatile("s_waitcnt vmcnt(4)" ::: "memory");
    } else {
      asm volatile("s_waitcnt vmcnt(0)" ::: "memory");
    }
    BARRIER();
    // fragment reads: row-major 64B rows, swizzled 16B slot (conflict-free)
#pragma unroll
    for (int ar = 0; ar < 4; ++ar)
#pragma unroll
      for (int ks = 0; ks < 2; ++ks)
        aF[ar][ks] = *reinterpret_cast<const bf16x8*>(
            smem + bo + (wr * 128 + ar * 32 + l31) * 64 +
            ((((ks << 1) + l32) ^ lsw) << 4));
#pragma unroll
    for (int n = 0; n < 2; ++n)
#pragma unroll
      for (int ks = 0; ks < 2; ++ks)
        bF[n][ks] = *reinterpret_cast<const bf16x8*>(
            smem + bo + 16384 + (wc * 64 + n * 32 + l31) * 64 +
            ((((ks << 1) + l32) ^ lsw) << 4));
    __builtin_amdgcn_s_setprio(1);
#pragma unroll
    for (int ar = 0; ar < 4; ++ar)
#pragma unroll
      for (int n = 0; n < 2; ++n) {
        acc[ar][n] = __builtin_amdgcn_mfma_f32_32x32x16_bf16(
            aF[ar][0], bF[n][0], acc[ar][n], 0, 0, 0);
        acc[ar][n] = __builtin_amdgcn_mfma_f32_32x32x16_bf16(
            aF[ar][1], bF[n][1], acc[ar][n], 0, 0, 0);
      }
    __builtin_amdgcn_s_setprio(0);
    BARRIER();   // all reads of buf[T&3] done before it is overwritten (T+1 stages T+4)
  }

  // ---------------- epilogue: bias + 2.0 * inter @ lb^T ----------------
  __syncthreads();
  float* interS = reinterpret_cast<float*>(smem);           // 256 x 16 f32 (broadcast)
  float* lbS    = reinterpret_cast<float*>(smem + 16384);   // 256 x 17 f32 (padded)
  const int e = eid[brow >> 11];
  const float* interG = inter + (size_t)brow * RNK;
  const float* lbG    = lb + ((size_t)e * N_TOT + bcol) * RNK;
#pragma unroll
  for (int q = 0; q < 8; ++q) {
    const int idx = t + 512 * q;
    interS[idx] = interG[idx];
    lbS[(idx >> 4) * 17 + (idx & 15)] = lbG[idx];
  }
  __syncthreads();

  // C/D layout (32x32): col = lane&31, row = (r&3) + 8*(r>>2) + 4*(lane>>5)
  const int ccol = wc * 64 + l31;
  float bv[2];
#pragma unroll
  for (int n = 0; n < 2; ++n)
    bv[n] = bias[bcol + ccol + n * 32];

#pragma unroll
  for (int ar = 0; ar < 4; ++ar) {
#pragma unroll
    for (int r = 0; r < 16; ++r) {
      const int ml = wr * 128 + ar * 32 + (r & 3) + 8 * (r >> 2) + 4 * l32;
      const float* iv = interS + ml * RNK;
      const size_t orow = (size_t)(brow + ml) * N_TOT + bcol;
#pragma unroll
      for (int n = 0; n < 2; ++n) {
        const int ol = ccol + n * 32;
        const float* lv = lbS + ol * 17;
        float d = 0.f;
#pragma unroll
        for (int rr = 0; rr < RNK; ++rr) d += iv[rr] * lv[rr];
        out[orow + ol] = acc[ar][n][r] + bv[n] + 2.0f * d;
      }
    }
  }
}

extern "C" void kernel_launch(void* const* d_in, const int* in_sizes, int n_in,
                              void* d_out, int out_size, void* d_ws, size_t ws_size,
                              hipStream_t stream) {
  const float* x    = (const float*)d_in[0];
  const int*   eid  = (const int*)d_in[1];
  const float* W    = (const float*)d_in[2];
  const float* bias = (const float*)d_in[3];
  const float* la   = (const float*)d_in[4];
  const float* lb   = (const float*)d_in[5];
  float* out = (float*)d_out;

  // workspace layout: xb (134MB) | wb (33.5MB) | inter (1MB)
  unsigned short* xb = (unsigned short*)d_ws;
  unsigned short* wb = xb + (size_t)M_TOT * K_TOT;
  float* inter = (float*)(wb + (size_t)N_TOT * K_TOT);

  cvt_f32_bf16<<<2048, 256, 0, stream>>>(W, wb, (N_TOT * K_TOT) / 4);
  xcvt_inter_kernel<<<M_TOT / 8, 256, 0, stream>>>(x, eid, la, xb, inter);

  gemm_kernel<<<(M_TOT / BM) * (N_TOT / BN), 512, 0, stream>>>(
      xb, wb, bias, inter, lb, eid, out);
}